// Round 15
// baseline (252.720 us; speedup 1.0000x reference)
//
#include <hip/hip_runtime.h>
#include <stdint.h>

typedef unsigned short u16;
typedef __attribute__((ext_vector_type(8))) short bf16x8;
typedef __attribute__((ext_vector_type(4))) float f32x4;

#define DEVI static __device__ __forceinline__

DEVI u16 f2bf(float f){
  union { float f; uint32_t u; } c; c.f = f;
  uint32_t u = c.u;
  u += 0x7FFFu + ((u >> 16) & 1u);   // RNE
  return (u16)(u >> 16);
}
DEVI float b2f(u16 h){
  union { uint32_t u; float f; } c; c.u = ((uint32_t)h) << 16;
  return c.f;
}

// async global->LDS, 16B per lane. LDS dest = wave-uniform base + lane*16.
DEVI void gload16(const u16* g, u16* l){
  __builtin_amdgcn_global_load_lds(
      (const __attribute__((address_space(1))) unsigned int*)g,
      (__attribute__((address_space(3))) unsigned int*)l, 16, 0, 0);
}

DEVI bf16x8 ldsrd(const void* base, int byte){
  return *reinterpret_cast<const bf16x8*>((const char*)base + byte);
}

// ---------------------------------------------------------------------------
// GEMM: C[m,n] = sum_k A[m,k] * Bt[n,k]
// m97 structure: global_load_lds width=16, both-sides LDS XOR swizzle.
// BIAS: 0 none, 1 bias[row], 2 bias[col]
// EPI : 0 f32 store   1 f32 +=   2 bf16 store   3 bf16 g*v + xadd[row,col]
//       7 bf16 store + per-block BN partials {sum,sumsq} -> red (no atomics)
// SWZ : 1 = bijective XCD-aware tile remap
// KSPLIT: >1 -> z enumerates (batch, k-chunk); C written per-slab
// ---------------------------------------------------------------------------
template<int BM,int BN,int FM,int FN,int BIAS,int EPI,int SWZ,int KSPLIT=1>
__global__ __launch_bounds__(256) void gemm_bt(
    const u16* __restrict__ A, long long strideA, int lda,
    const u16* __restrict__ B, long long strideB, int ldb,
    void* __restrict__ C, long long strideC, int ldc,
    const float* __restrict__ bias, int K,
    const float* __restrict__ cscale, const u16* __restrict__ xadd,
    long long strideX, int ldx, float* __restrict__ red)
{
  constexpr int BK  = 32;                 // 64B per LDS row
  constexpr int WTM = FM*16, WTN = FN*16;
  static_assert(BM == 2*WTM && BN == 2*WTN, "2x2 wave layout");
  __shared__ u16 As[BM*BK];
  __shared__ u16 Bs[BN*BK];

  int bx = blockIdx.x, by = blockIdx.y, bz = blockIdx.z;
  if(SWZ){
    const int gx = gridDim.x, gy = gridDim.y;
    const int nwg = gx * gy * gridDim.z;
    const int orig = bx + gx * (by + gy * bz);
    const int q = nwg >> 3, r = nwg & 7;
    const int xcd = orig & 7, i = orig >> 3;
    const int wg = (xcd < r ? xcd*(q+1) : r*(q+1) + (xcd-r)*q) + i;
    bx = wg % gx;
    const int t = wg / gx;
    by = t % gy;
    bz = t / gy;
  }

  const int zz = bz;
  const int z  = (KSPLIT > 1) ? zz / KSPLIT : zz;
  const int ks = (KSPLIT > 1) ? zz % KSPLIT : 0;
  const u16* Ab = A + (long long)z * strideA + (long long)ks * K;
  const u16* Bb = B + (long long)z * strideB + (long long)ks * K;

  const int tid  = threadIdx.x;
  const int lane = tid & 63, wid = tid >> 6;
  const int wr = wid >> 1, wc = wid & 1;
  const long long bm0 = (long long)by * BM;
  const long long bn0 = (long long)bx * BN;

  const int srow  = lane >> 2;
  const int scol  = (((lane & 3) ^ ((lane >> 3) & 3))) * 8;   // bf16 col
  const int wrow  = wid * 16 + srow;
  constexpr int TA = BM/64, TB = BN/64;

  const int fr  = lane & 15;
  const int sl8 = ((lane >> 4) ^ ((lane >> 1) & 3)) * 8;

  f32x4 acc[FM][FN] = {};

  for(int k0 = 0; k0 < K; k0 += BK){
    __syncthreads();
    #pragma unroll
    for(int t=0;t<TA;t++)
      gload16(&Ab[(bm0 + t*64 + wrow)*lda + k0 + scol],
              &As[(t*64 + wid*16)*BK]);
    #pragma unroll
    for(int t=0;t<TB;t++)
      gload16(&Bb[(bn0 + t*64 + wrow)*ldb + k0 + scol],
              &Bs[(t*64 + wid*16)*BK]);
    __syncthreads();

    bf16x8 af[FM], bg[FN];
    #pragma unroll
    for(int m=0;m<FM;m++)
      af[m] = *reinterpret_cast<const bf16x8*>(&As[(wr*WTM + m*16 + fr)*BK + sl8]);
    #pragma unroll
    for(int n=0;n<FN;n++)
      bg[n] = *reinterpret_cast<const bf16x8*>(&Bs[(wc*WTN + n*16 + fr)*BK + sl8]);
    #pragma unroll
    for(int m=0;m<FM;m++)
      #pragma unroll
      for(int n=0;n<FN;n++)
        acc[m][n] = __builtin_amdgcn_mfma_f32_16x16x32_bf16(af[m], bg[n], acc[m][n], 0, 0, 0);
  }

  // C/D layout (verified m89): col = lane&15, row = (lane>>4)*4 + reg
  const int lr = (lane >> 4) * 4, lc = lane & 15;

  if(EPI == 7){
    // bf16 store + per-block BN partials (deterministic slots, no atomics)
    u16* Cp = (u16*)C + (long long)zz*strideC;
    #pragma unroll
    for(int m=0;m<FM;m++){
      #pragma unroll
      for(int r=0;r<4;r++){
        long long row = bm0 + wr*WTM + m*16 + lr + r;
        float bv = bias[(int)row];
        float s = 0.f, ss = 0.f;
        #pragma unroll
        for(int n=0;n<FN;n++){
          long long col = bn0 + wc*WTN + n*16 + lc;
          float v = acc[m][n][r] + bv;
          Cp[row*(long long)ldc + col] = f2bf(v);
          s += v; ss += v*v;
        }
        #pragma unroll
        for(int o=1;o<16;o<<=1){ s += __shfl_xor(s, o); ss += __shfl_xor(ss, o); }
        if(lc == 0){
          int slot = (z*(int)gridDim.x + bx)*2 + wc;    // 256 slots per channel
          red[(int)row*512 + slot*2]     = s;
          red[(int)row*512 + slot*2 + 1] = ss;
        }
      }
    }
    return;
  }

  const float g = (EPI == 3) ? cscale[0] : 0.f;
  #pragma unroll
  for(int m=0;m<FM;m++){
    #pragma unroll
    for(int n=0;n<FN;n++){
      #pragma unroll
      for(int r=0;r<4;r++){
        long long row = bm0 + wr*WTM + m*16 + lr + r;
        long long col = bn0 + wc*WTN + n*16 + lc;
        float v = acc[m][n][r];
        if(BIAS == 1) v += bias[(int)row];
        if(BIAS == 2) v += bias[(int)col];
        long long idx = row * (long long)ldc + col;
        if(EPI == 0){
          ((float*)C + (long long)zz*strideC)[idx] = v;
        } else if(EPI == 1){
          ((float*)C + (long long)zz*strideC)[idx] += v;
        } else if(EPI == 2){
          ((u16*)C + (long long)zz*strideC)[idx] = f2bf(v);
        } else {
          float xv = b2f(xadd[(long long)z*strideX + row*(long long)ldx + col]);
          ((u16*)C + (long long)zz*strideC)[idx] = f2bf(g * v + xv);
        }
      }
    }
  }
}

// ---------------------------------------------------------------------------
// Fused position attention (flash-style, unnormalized exp):
//   posT[n, c] = gamma/rowsum[n] * sum_j exp(q_n . k_j) v[c, j] + xfT[n, c]
// Block: 64 q-rows x 256 v-channels (c-half), 8 waves (wr 2 x wc 4):
//   QK: wave computes S[32q][16k];  PV: wave computes O[32q][64c]
// 512 blocks x 57KB LDS -> 2 blocks/CU, 4 waves/SIMD (cross-block overlap).
// K double-buffered, V single-buffered (issue-after-B2 / drain-at-B1).
// LDS [rows][64] bf16, byte ^= (row&7)<<4 swizzle; since row&7 == fr&7 for
// all fragment reads, each read family needs ONE base register.
// (r7 structure — measured optimum across 5 structural variants; do not touch)
// ---------------------------------------------------------------------------
__global__ __launch_bounds__(512, 4) void flash_pos(
    const u16* __restrict__ qkT,   // [b][4096][128]  q cols 0-63, k cols 64-127
    const u16* __restrict__ vB,    // [b][512][4096]
    const u16* __restrict__ xfT,   // [b][4096][512]
    u16* __restrict__ pcT,         // [b][4096][1024], pos -> cols 0-511
    const float* __restrict__ gamma)
{
  __shared__ u16 Ks[2][64*64];      // 16KB
  __shared__ u16 Vs[256*64];        // 32KB (single-buffered)
  __shared__ u16 Ps[64*64];         // 8KB
  __shared__ float RS[2][4][32];    // rowsum partials per (wr, wc)

  // XCD chunk swizzle: 512 blocks; 64 consecutive (one (ch,z) slice) per XCD
  int flat = blockIdx.x + 64*(blockIdx.y + 2*blockIdx.z);
  flat = (flat & 7)*64 + (flat >> 3);
  const int bx = flat & 63;          // q-block (64 rows)
  const int ch = (flat >> 6) & 1;    // c-half (256 channels)
  const int z  = flat >> 7;          // batch

  const int q0 = bx*64, c0 = ch*256;
  const int tid = threadIdx.x, lane = tid & 63, wid = tid >> 6;
  const int wr = wid >> 2, wc = wid & 3;
  const int fr = lane & 15, fq = lane >> 4;

  const u16* qkb = qkT + (long long)z*4096*128;
  const u16* vbb = vB  + (long long)z*512*4096;

  // staging geometry: one call = 512 thr x 16B = 8KB = 64 rows of 128B.
  const int srow  = lane >> 3;
  const int sslot = (lane & 7) ^ srow;       // pre-swizzled 16B source slot

  // Q fragments direct from global (loop-invariant, wave's 32 q-rows)
  bf16x8 qa[2][2];
  #pragma unroll
  for(int m=0;m<2;m++)
    #pragma unroll
    for(int kk=0;kk<2;kk++)
      qa[m][kk] = *reinterpret_cast<const bf16x8*>(
          &qkb[(long long)(q0 + wr*32 + m*16 + fr)*128 + kk*32 + fq*8]);

  // incrementing staging pointers (no per-iter 64-bit mul chains)
  const u16* kp  = qkb + (long long)(wid*8 + srow)*128 + 64 + sslot*8;
  const u16* vp0 = vbb + (long long)(c0 + wid*8 + srow)*4096 + sslot*8;

  // precomputed LDS fragment base offsets (swizzle mask = (fr&7)<<4 for all)
  const int xm   = (fr & 7) << 4;
  const int koff = (wc*16 + fr)*128 + ((fq*16) ^ xm);   // K frag (kk: ^64)
  const int pab  = (wr*32 + fr)*128 + ((fq*16) ^ xm);   // P frag (+m*2048, ^kk*64)
  const int vfb  = (wc*64 + fr)*128 + ((fq*16) ^ xm);   // V frag (+n*2048, ^kk*64)
  const int kdst = wid * 1024;                          // K staging LDS offset
  // P write offsets per r (row qr = fq*4+r; + wr*4096 + m*2048 at store)
  const int key2 = (wc*16 + fr)*2;
  int pwo[4];
  #pragma unroll
  for(int r=0;r<4;r++){
    int qr = fq*4 + r;
    pwo[r] = qr*128 + (key2 ^ ((qr & 7) << 4));
  }

  // prologue: K0 (1 call), V0 (4 calls)
  gload16(kp, (u16*)((char*)Ks + kdst));
  kp += 64*128;
  gload16(vp0,            &Vs[(  0 + wid*8)*64]);
  gload16(vp0 +  64*4096, &Vs[( 64 + wid*8)*64]);
  gload16(vp0 + 128*4096, &Vs[(128 + wid*8)*64]);
  gload16(vp0 + 192*4096, &Vs[(192 + wid*8)*64]);
  vp0 += 64;
  __syncthreads();

  f32x4 acc[2][4] = {};
  float rsacc[2][4] = {};

  for(int t=0;t<64;t++){
    const int kbase = (t & 1) ? 8192 : 0;
    // ---- S = Q . K^T: this wave's 32q x 16k tile ----
    bf16x8 kb0 = ldsrd(Ks, kbase + koff);
    bf16x8 kb1 = ldsrd(Ks, kbase + (koff ^ 64));
    f32x4 s[2] = {};
    #pragma unroll
    for(int m=0;m<2;m++){
      s[m] = __builtin_amdgcn_mfma_f32_16x16x32_bf16(qa[m][0], kb0, s[m], 0, 0, 0);
      s[m] = __builtin_amdgcn_mfma_f32_16x16x32_bf16(qa[m][1], kb1, s[m], 0, 0, 0);
    }

    // ---- P = exp(S) -> LDS (swizzled), accumulate row-sum partials ----
    #pragma unroll
    for(int m=0;m<2;m++){
      #pragma unroll
      for(int r=0;r<4;r++){
        float e = __expf(s[m][r]);
        rsacc[m][r] += e;
        *(u16*)((char*)Ps + (pwo[r] + wr*4096 + m*2048)) = f2bf(e);
      }
    }
    __syncthreads();   // B1: P visible; V(t) stage (issued end of t-1) drained

    // issue next K staging (drained at B2, hidden under PV)
    if(t+1 < 64){
      gload16(kp, (u16*)((char*)Ks + (kbase ^ 8192) + kdst));
      kp += 64*128;
    }

    // ---- PV: acc[32q x 64c] += P . V^T ----
    bf16x8 pa00 = ldsrd(Ps, pab);
    bf16x8 pa01 = ldsrd(Ps, pab ^ 64);
    bf16x8 pa10 = ldsrd(Ps, (pab + 2048));
    bf16x8 pa11 = ldsrd(Ps, (pab + 2048) ^ 64);
    __builtin_amdgcn_s_setprio(1);
    #pragma unroll
    for(int n=0;n<4;n++){
      bf16x8 v0 = ldsrd(Vs, vfb + n*2048);
      bf16x8 v1 = ldsrd(Vs, (vfb + n*2048) ^ 64);
      acc[0][n] = __builtin_amdgcn_mfma_f32_16x16x32_bf16(pa00, v0, acc[0][n], 0, 0, 0);
      acc[0][n] = __builtin_amdgcn_mfma_f32_16x16x32_bf16(pa01, v1, acc[0][n], 0, 0, 0);
      acc[1][n] = __builtin_amdgcn_mfma_f32_16x16x32_bf16(pa10, v0, acc[1][n], 0, 0, 0);
      acc[1][n] = __builtin_amdgcn_mfma_f32_16x16x32_bf16(pa11, v1, acc[1][n], 0, 0, 0);
    }
    __builtin_amdgcn_s_setprio(0);
    __syncthreads();   // B2: all Ps/Vs reads done; K(t+1) drained

    // issue next V staging (flies during QK/exp(t+1), drained at next B1)
    if(t+1 < 64){
      gload16(vp0,            &Vs[(  0 + wid*8)*64]);
      gload16(vp0 +  64*4096, &Vs[( 64 + wid*8)*64]);
      gload16(vp0 + 128*4096, &Vs[(128 + wid*8)*64]);
      gload16(vp0 + 192*4096, &Vs[(192 + wid*8)*64]);
      vp0 += 64;
    }
  }

  // ---- rowsum: reduce over the 16 key-lanes, then across wc quarters ----
  #pragma unroll
  for(int m=0;m<2;m++)
    #pragma unroll
    for(int r=0;r<4;r++){
      float v = rsacc[m][r];
      #pragma unroll
      for(int o=1;o<16;o<<=1) v += __shfl_xor(v, o);
      rsacc[m][r] = v;
    }
  if(fr == 0){
    #pragma unroll
    for(int m=0;m<2;m++)
      #pragma unroll
      for(int r=0;r<4;r++)
        RS[wr][wc][m*16 + fq*4 + r] = rsacc[m][r];
  }
  __syncthreads();

  const float g = gamma[0];
  #pragma unroll
  for(int m=0;m<2;m++){
    float inv[4];
    #pragma unroll
    for(int r=0;r<4;r++){
      int rloc = m*16 + fq*4 + r;
      inv[r] = g / (RS[wr][0][rloc] + RS[wr][1][rloc] +
                    RS[wr][2][rloc] + RS[wr][3][rloc]);
    }
    #pragma unroll
    for(int n=0;n<4;n++){
      #pragma unroll
      for(int r=0;r<4;r++){
        int qrow = q0 + wr*32 + m*16 + fq*4 + r;
        int c    = c0 + wc*64 + n*16 + fr;
        float xv = b2f(xfT[((long long)z*4096 + qrow)*512 + c]);
        pcT[((long long)z*4096 + qrow)*1024 + c] = f2bf(acc[m][n][r]*inv[r] + xv);
      }
    }
  }
}

// ---------------------------------------------------------------------------
// Channel softmax over 8 split-K bf16 partial slabs:
// catt[b][i][j] = softmax_j( sum_s part[b*8+s][i][j] )
// ---------------------------------------------------------------------------
__global__ __launch_bounds__(256) void softmax_sum8b(const u16* __restrict__ part,
                                                     u16* __restrict__ catt)
{
  const int row = blockIdx.x;            // b*512 + i
  const int b = row >> 9, i = row & 511;
  const int t = threadIdx.x;
  const int lane = t & 63, wid = t >> 6;
  float v0 = 0.f, v1 = 0.f;
  #pragma unroll
  for(int sl=0;sl<8;sl++){
    uint32_t pr = *reinterpret_cast<const uint32_t*>(
        &part[(((long long)(b*8 + sl)*512 + i)*512) + 2*t]);
    v0 += b2f((u16)pr);
    v1 += b2f((u16)(pr >> 16));
  }
  float m = fmaxf(v0, v1);
  #pragma unroll
  for(int o=32;o;o>>=1) m = fmaxf(m, __shfl_xor(m, o));
  __shared__ float sred[4];
  if(lane == 0) sred[wid] = m;
  __syncthreads();
  m = fmaxf(fmaxf(sred[0], sred[1]), fmaxf(sred[2], sred[3]));
  float e0 = __expf(v0 - m), e1 = __expf(v1 - m);
  float s = e0 + e1;
  #pragma unroll
  for(int o=32;o;o>>=1) s += __shfl_xor(s, o);
  __syncthreads();
  if(lane == 0) sred[wid] = s;
  __syncthreads();
  s = sred[0] + sred[1] + sred[2] + sred[3];
  float inv = 1.0f / s;
  uint32_t pk = (uint32_t)f2bf(e0 * inv) | ((uint32_t)f2bf(e1 * inv) << 16);
  *reinterpret_cast<uint32_t*>(&catt[(long long)row * 512 + 2*t]) = pk;
}

// ---------------------------------------------------------------------------
// One-shot weight prep: qw/kw/vw/fw f32 -> bf16 (float4 granularity) + bias cat
// ---------------------------------------------------------------------------
__global__ __launch_bounds__(256) void prep_weights(
    const float* __restrict__ qw, const float* __restrict__ kw,
    const float* __restrict__ vw, const float* __restrict__ fw,
    const float* __restrict__ qb, const float* __restrict__ kb,
    u16* __restrict__ qkwb, u16* __restrict__ vwb, u16* __restrict__ fwb,
    float* __restrict__ qkb)
{
  long long i = (long long)blockIdx.x*256 + threadIdx.x;
  const float* src; u16* dst; long long o;
  if(i < 8192){        src = qw; dst = qkwb;          o = i; }
  else if(i < 16384){  src = kw; dst = qkwb + 32768;  o = i - 8192; }
  else if(i < 81920){  src = vw; dst = vwb;           o = i - 16384; }
  else if(i < 212992){ src = fw; dst = fwb;           o = i - 81920; }
  else if(i < 213024){
    int t = (int)(i - 212992) * 4;
    #pragma unroll
    for(int j=0;j<4;j++) qkb[t+j] = (t+j < 64) ? qb[t+j] : kb[t+j-64];
    return;
  } else return;
  float4 v = reinterpret_cast<const float4*>(src)[o];
  ushort4 w;
  w.x = f2bf(v.x); w.y = f2bf(v.y); w.z = f2bf(v.z); w.w = f2bf(v.w);
  reinterpret_cast<ushort4*>(dst)[o] = w;
}

// x f32 [b][512][4096] -> xfb bf16 [b][512][4096] and xfT bf16 [b][4096][512]
__global__ __launch_bounds__(256) void transpose_cast(
    const float* __restrict__ x, u16* __restrict__ xfb, u16* __restrict__ xfT)
{
  __shared__ float tile[32][33];
  const int b  = blockIdx.z;
  const int n0 = blockIdx.x * 32, c0 = blockIdx.y * 32;
  const int tx = threadIdx.x, ty = threadIdx.y;  // 32 x 8
  const float* xp = x + (long long)b * 512 * 4096;
  #pragma unroll
  for(int i=0;i<4;i++){
    int c = c0 + ty + i*8;
    float v = xp[(long long)c*4096 + n0 + tx];
    tile[ty + i*8][tx] = v;
    xfb[((long long)b*512 + c)*4096 + n0 + tx] = f2bf(v);
  }
  __syncthreads();
  #pragma unroll
  for(int i=0;i<4;i++){
    int n = n0 + ty + i*8;
    xfT[((long long)b*4096 + n)*512 + c0 + tx] = f2bf(tile[tx][ty + i*8]);
  }
}

// reduce fusion-GEMM BN partials: red[512][256][2] -> stat {mean, rstd}
__global__ __launch_bounds__(256) void bn_finalize(const float* __restrict__ red,
                                                   float* __restrict__ stat)
{
  int ch = blockIdx.x*256 + threadIdx.x;
  if(ch >= 512) return;
  float s = 0.f, ss = 0.f;
  for(int j=0;j<256;j++){
    s  += red[ch*512 + j*2];
    ss += red[ch*512 + j*2 + 1];
  }
  float mean = s * (1.f/16384.f);
  float var  = ss * (1.f/16384.f) - mean*mean;
  stat[ch*2]   = mean;
  stat[ch*2+1] = rsqrtf(var + 1e-5f);
}

// out = relu((y_bf16 - mean)*rstd*w + b), 8 elems/thread
__global__ __launch_bounds__(256) void bn_apply_b(const u16* __restrict__ y,
    const float* __restrict__ stat, const float* __restrict__ w,
    const float* __restrict__ bb, float* __restrict__ out)
{
  long long i = (long long)blockIdx.x*256 + threadIdx.x;   // 8-elem unit
  bf16x8 v = *reinterpret_cast<const bf16x8*>(&y[i*8]);
  int o = (int)(((i*8) >> 12) & 511);
  float sc = w[o] * stat[o*2+1];
  float sh = bb[o] - stat[o*2] * sc;
  float4 lo, hi;
  lo.x = fmaxf(b2f((u16)v[0])*sc + sh, 0.f);
  lo.y = fmaxf(b2f((u16)v[1])*sc + sh, 0.f);
  lo.z = fmaxf(b2f((u16)v[2])*sc + sh, 0.f);
  lo.w = fmaxf(b2f((u16)v[3])*sc + sh, 0.f);
  hi.x = fmaxf(b2f((u16)v[4])*sc + sh, 0.f);
  hi.y = fmaxf(b2f((u16)v[5])*sc + sh, 0.f);
  hi.z = fmaxf(b2f((u16)v[6])*sc + sh, 0.f);
  hi.w = fmaxf(b2f((u16)v[7])*sc + sh, 0.f);
  *reinterpret_cast<float4*>(&out[i*8])     = lo;
  *reinterpret_cast<float4*>(&out[i*8 + 4]) = hi;
}

extern "C" void kernel_launch(void* const* d_in, const int* in_sizes, int n_in,
                              void* d_out, int out_size, void* d_ws, size_t ws_size,
                              hipStream_t stream)
{
  const float* x     = (const float*)d_in[0];
  const float* qw    = (const float*)d_in[1];
  const float* qb    = (const float*)d_in[2];
  const float* kw    = (const float*)d_in[3];
  const float* kb    = (const float*)d_in[4];
  const float* vw    = (const float*)d_in[5];
  const float* vb    = (const float*)d_in[6];
  const float* gamma = (const float*)d_in[7];
  const float* beta  = (const float*)d_in[8];
  const float* fw    = (const float*)d_in[9];
  const float* fb    = (const float*)d_in[10];
  const float* bnw   = (const float*)d_in[11];
  const float* bnb   = (const float*)d_in[12];
  float* out = (float*)d_out;
  (void)in_sizes; (void)n_in; (void)out_size; (void)ws_size;

  char* base = (char*)d_ws;
  size_t off = 0;
  auto alloc = [&](size_t bytes)->char* {
    char* p = base + off;
    off += (bytes + 255) & ~(size_t)255;
    return p;
  };
  const long long NB = 4, Cc = 512, Nn = 4096;

  u16*   xfT  = (u16*)alloc((size_t)NB*Nn*Cc*2);     // [b][n][c]
  u16*   fwb  = (u16*)alloc((size_t)Cc*2*Cc*2);      // [512][1024] (alive thru fusion)
  // --- region dead by fusion time: ybf16 aliases it (needs 33.6MB; has ~38.5) ---
  char*  region = (char*)(base + off);
  u16*   xfb  = (u16*)alloc((size_t)NB*Cc*Nn*2);     // [b][c][n]
  u16*   qkwb = (u16*)alloc((size_t)128*Cc*2);       // [128][512]
  float* qkb  = (float*)alloc(128*4);
  u16*   vwb  = (u16*)alloc((size_t)Cc*Cc*2);
  u16*   qkT  = (u16*)alloc((size_t)NB*Nn*128*2);    // [b][n][128]
  u16*   vB   = (u16*)alloc((size_t)NB*Cc*Nn*2);     // [b][c][n]
  // --- end region ---
  u16*   pcT  = (u16*)alloc((size_t)NB*Nn*1024*2);   // [b][n][pos|chan]
  u16*   epart= (u16*)alloc((size_t)32*Cc*Cc*2);     // energy partials bf16 [b*8+s]
  u16*   catt = (u16*)alloc((size_t)NB*Cc*Cc*2);
  float* stat = (float*)alloc((size_t)Cc*2*4);
  float* red  = (float*)alloc((size_t)Cc*256*2*4);   // BN partials [512][256][2]
  u16*   ybf16= (u16*)region;                        // [b][512][4096] bf16

  // --- weights to bf16 (+ q/k stacked, bias concat) — one launch ---
  prep_weights<<<dim3(833), dim3(256), 0, stream>>>(qw, kw, vw, fw, qb, kb,
                                                    qkwb, vwb, fwb, qkb);
  // --- x -> xfb, xfT ---
  transpose_cast<<<dim3(128,16,4), dim3(32,8), 0, stream>>>(x, xfb, xfT);

  // --- projections: qkT[n,0:64]=q, [64:128]=k ; vB[c,n] ---
  gemm_bt<64,128,2,4,2,2,1><<<dim3(1,64,4), dim3(256), 0, stream>>>(
      xfT, Nn*Cc, 512, qkwb, 0, 512, qkT, Nn*128, 128, qkb, 512,
      nullptr, nullptr, 0, 0, nullptr);
  gemm_bt<128,128,4,4,1,2,1><<<dim3(32,4,4), dim3(256), 0, stream>>>(
      vwb, 0, 512, xfT, Nn*Cc, 512, vB, Cc*Nn, 4096, vb, 512,
      nullptr, nullptr, 0, 0, nullptr);

  // --- channel attention: energy (128^2 tile, split-K 8, bf16 partials) ---
  gemm_bt<128,128,4,4,0,2,1,8><<<dim3(4,4,32), dim3(256), 0, stream>>>(
      xfb, Cc*Nn, 4096, xfb, Cc*Nn, 4096, epart, Cc*Cc, 512, nullptr, 512,
      nullptr, nullptr, 0, 0, nullptr);
  softmax_sum8b<<<dim3(2048), dim3(256), 0, stream>>>(epart, catt);
  gemm_bt<128,128,4,4,0,3,1><<<dim3(4,32,4), dim3(256), 0, stream>>>(
      xfT, Nn*Cc, 512, catt, Cc*Cc, 512, pcT + 512, Nn*1024, 1024, nullptr, 512,
      beta, xfT, Nn*Cc, 512, nullptr);

  // --- position attention: fused flash kernel (pcT cols 0-511) ---
  flash_pos<<<dim3(64,2,4), dim3(512), 0, stream>>>(qkT, vB, xfT, pcT, gamma);

  // --- fusion conv: ybf16 = fw . [pos|chan] + fb, fused BN partials ---
  gemm_bt<128,128,4,4,1,7,1><<<dim3(32,4,4), dim3(256), 0, stream>>>(
      fwb, 0, 1024, pcT, Nn*1024, 1024, ybf16, Cc*Nn, 4096, fb, 1024,
      nullptr, nullptr, 0, 0, red);

  // --- BN finalize + apply (+ReLU) into f32 out ---
  bn_finalize<<<dim3(2), dim3(256), 0, stream>>>(red, stat);
  bn_apply_b<<<dim3(4096), dim3(256), 0, stream>>>(ybf16, stat, bnw, bnb, out);
}

// Round 16
// 234.355 us; speedup vs baseline: 1.0784x; 1.0784x over previous
//
#include <hip/hip_runtime.h>
#include <stdint.h>

typedef unsigned short u16;
typedef __attribute__((ext_vector_type(8))) short bf16x8;
typedef __attribute__((ext_vector_type(4))) float f32x4;

#define DEVI static __device__ __forceinline__

DEVI u16 f2bf(float f){
  union { float f; uint32_t u; } c; c.f = f;
  uint32_t u = c.u;
  u += 0x7FFFu + ((u >> 16) & 1u);   // RNE
  return (u16)(u >> 16);
}
DEVI float b2f(u16 h){
  union { uint32_t u; float f; } c; c.u = ((uint32_t)h) << 16;
  return c.f;
}

// async global->LDS, 16B per lane. LDS dest = wave-uniform base + lane*16.
DEVI void gload16(const u16* g, u16* l){
  __builtin_amdgcn_global_load_lds(
      (const __attribute__((address_space(1))) unsigned int*)g,
      (__attribute__((address_space(3))) unsigned int*)l, 16, 0, 0);
}

DEVI bf16x8 ldsrd(const void* base, int byte){
  return *reinterpret_cast<const bf16x8*>((const char*)base + byte);
}

// ---------------------------------------------------------------------------
// GEMM: C[m,n] = sum_k A[m,k] * Bt[n,k]
// m97 structure: global_load_lds width=16, both-sides LDS XOR swizzle.
// BIAS: 0 none, 1 bias[row], 2 bias[col]
// EPI : 0 f32 store   1 f32 +=   2 bf16 store   3 bf16 g*v + xadd[row,col]
//       9 bf16 store (token-major) + per-COLUMN BN partials -> red (no atomics)
// SWZ : 1 = bijective XCD-aware tile remap
// KSPLIT: >1 -> z enumerates (batch, k-chunk); C written per-slab
// ---------------------------------------------------------------------------
template<int BM,int BN,int FM,int FN,int BIAS,int EPI,int SWZ,int KSPLIT=1>
__global__ __launch_bounds__(256) void gemm_bt(
    const u16* __restrict__ A, long long strideA, int lda,
    const u16* __restrict__ B, long long strideB, int ldb,
    void* __restrict__ C, long long strideC, int ldc,
    const float* __restrict__ bias, int K,
    const float* __restrict__ cscale, const u16* __restrict__ xadd,
    long long strideX, int ldx, float* __restrict__ red)
{
  constexpr int BK  = 32;                 // 64B per LDS row
  constexpr int WTM = FM*16, WTN = FN*16;
  static_assert(BM == 2*WTM && BN == 2*WTN, "2x2 wave layout");
  __shared__ u16 As[BM*BK];
  __shared__ u16 Bs[BN*BK];

  int bx = blockIdx.x, by = blockIdx.y, bz = blockIdx.z;
  if(SWZ){
    const int gx = gridDim.x, gy = gridDim.y;
    const int nwg = gx * gy * gridDim.z;
    const int orig = bx + gx * (by + gy * bz);
    const int q = nwg >> 3, r = nwg & 7;
    const int xcd = orig & 7, i = orig >> 3;
    const int wg = (xcd < r ? xcd*(q+1) : r*(q+1) + (xcd-r)*q) + i;
    bx = wg % gx;
    const int t = wg / gx;
    by = t % gy;
    bz = t / gy;
  }

  const int zz = bz;
  const int z  = (KSPLIT > 1) ? zz / KSPLIT : zz;
  const int ks = (KSPLIT > 1) ? zz % KSPLIT : 0;
  const u16* Ab = A + (long long)z * strideA + (long long)ks * K;
  const u16* Bb = B + (long long)z * strideB + (long long)ks * K;

  const int tid  = threadIdx.x;
  const int lane = tid & 63, wid = tid >> 6;
  const int wr = wid >> 1, wc = wid & 1;
  const long long bm0 = (long long)by * BM;
  const long long bn0 = (long long)bx * BN;

  const int srow  = lane >> 2;
  const int scol  = (((lane & 3) ^ ((lane >> 3) & 3))) * 8;   // bf16 col
  const int wrow  = wid * 16 + srow;
  constexpr int TA = BM/64, TB = BN/64;

  const int fr  = lane & 15;
  const int sl8 = ((lane >> 4) ^ ((lane >> 1) & 3)) * 8;

  f32x4 acc[FM][FN] = {};

  for(int k0 = 0; k0 < K; k0 += BK){
    __syncthreads();
    #pragma unroll
    for(int t=0;t<TA;t++)
      gload16(&Ab[(bm0 + t*64 + wrow)*lda + k0 + scol],
              &As[(t*64 + wid*16)*BK]);
    #pragma unroll
    for(int t=0;t<TB;t++)
      gload16(&Bb[(bn0 + t*64 + wrow)*ldb + k0 + scol],
              &Bs[(t*64 + wid*16)*BK]);
    __syncthreads();

    bf16x8 af[FM], bg[FN];
    #pragma unroll
    for(int m=0;m<FM;m++)
      af[m] = *reinterpret_cast<const bf16x8*>(&As[(wr*WTM + m*16 + fr)*BK + sl8]);
    #pragma unroll
    for(int n=0;n<FN;n++)
      bg[n] = *reinterpret_cast<const bf16x8*>(&Bs[(wc*WTN + n*16 + fr)*BK + sl8]);
    #pragma unroll
    for(int m=0;m<FM;m++)
      #pragma unroll
      for(int n=0;n<FN;n++)
        acc[m][n] = __builtin_amdgcn_mfma_f32_16x16x32_bf16(af[m], bg[n], acc[m][n], 0, 0, 0);
  }

  // C/D layout (verified m89): col = lane&15, row = (lane>>4)*4 + reg
  const int lr = (lane >> 4) * 4, lc = lane & 15;

  if(EPI == 9){
    // yT[row=token][col=channel] = v + bias[col]; per-column BN partials.
    // Column's rows live in lanes {lc, lc+16, lc+32, lc+48}: reduce via
    // shfl_xor(16|32); slot = (z*gridDim.y + by)*2 + wr -> 256 slots/channel.
    u16* Cp = (u16*)C + (long long)zz*strideC;
    #pragma unroll
    for(int n=0;n<FN;n++){
      long long col = bn0 + wc*WTN + n*16 + lc;
      float bv = bias[(int)col];
      float s = 0.f, ss = 0.f;
      #pragma unroll
      for(int m=0;m<FM;m++){
        #pragma unroll
        for(int r=0;r<4;r++){
          long long row = bm0 + wr*WTM + m*16 + lr + r;
          float v = acc[m][n][r] + bv;
          Cp[row*(long long)ldc + col] = f2bf(v);
          s += v; ss += v*v;
        }
      }
      s += __shfl_xor(s,16); ss += __shfl_xor(ss,16);
      s += __shfl_xor(s,32); ss += __shfl_xor(ss,32);
      if(lane < 16){
        int slot = (z*(int)gridDim.y + by)*2 + wr;
        red[col*512 + slot*2]     = s;
        red[col*512 + slot*2 + 1] = ss;
      }
    }
    return;
  }

  const float g = (EPI == 3) ? cscale[0] : 0.f;
  #pragma unroll
  for(int m=0;m<FM;m++){
    #pragma unroll
    for(int n=0;n<FN;n++){
      #pragma unroll
      for(int r=0;r<4;r++){
        long long row = bm0 + wr*WTM + m*16 + lr + r;
        long long col = bn0 + wc*WTN + n*16 + lc;
        float v = acc[m][n][r];
        if(BIAS == 1) v += bias[(int)row];
        if(BIAS == 2) v += bias[(int)col];
        long long idx = row * (long long)ldc + col;
        if(EPI == 0){
          ((float*)C + (long long)zz*strideC)[idx] = v;
        } else if(EPI == 1){
          ((float*)C + (long long)zz*strideC)[idx] += v;
        } else if(EPI == 2){
          ((u16*)C + (long long)zz*strideC)[idx] = f2bf(v);
        } else {
          float xv = b2f(xadd[(long long)z*strideX + row*(long long)ldx + col]);
          ((u16*)C + (long long)zz*strideC)[idx] = f2bf(g * v + xv);
        }
      }
    }
  }
}

// ---------------------------------------------------------------------------
// Fused position attention (flash-style, unnormalized exp):
//   posT[n, c] = gamma/rowsum[n] * sum_j exp(q_n . k_j) v[c, j] + xfT[n, c]
// Block: 64 q-rows x 256 v-channels (c-half), 8 waves (wr 2 x wc 4):
//   QK: wave computes S[32q][16k];  PV: wave computes O[32q][64c]
// 512 blocks x 57KB LDS -> 2 blocks/CU, 4 waves/SIMD (cross-block overlap).
// K double-buffered, V single-buffered (issue-after-B2 / drain-at-B1).
// LDS [rows][64] bf16, byte ^= (row&7)<<4 swizzle; since row&7 == fr&7 for
// all fragment reads, each read family needs ONE base register.
// (r7 structure — measured optimum across 5 structural variants; do not touch)
// ---------------------------------------------------------------------------
__global__ __launch_bounds__(512, 4) void flash_pos(
    const u16* __restrict__ qkT,   // [b][4096][128]  q cols 0-63, k cols 64-127
    const u16* __restrict__ vB,    // [b][512][4096]
    const u16* __restrict__ xfT,   // [b][4096][512]
    u16* __restrict__ pcT,         // [b][4096][1024], pos -> cols 0-511
    const float* __restrict__ gamma)
{
  __shared__ u16 Ks[2][64*64];      // 16KB
  __shared__ u16 Vs[256*64];        // 32KB (single-buffered)
  __shared__ u16 Ps[64*64];         // 8KB
  __shared__ float RS[2][4][32];    // rowsum partials per (wr, wc)

  // XCD chunk swizzle: 512 blocks; 64 consecutive (one (ch,z) slice) per XCD
  int flat = blockIdx.x + 64*(blockIdx.y + 2*blockIdx.z);
  flat = (flat & 7)*64 + (flat >> 3);
  const int bx = flat & 63;          // q-block (64 rows)
  const int ch = (flat >> 6) & 1;    // c-half (256 channels)
  const int z  = flat >> 7;          // batch

  const int q0 = bx*64, c0 = ch*256;
  const int tid = threadIdx.x, lane = tid & 63, wid = tid >> 6;
  const int wr = wid >> 2, wc = wid & 3;
  const int fr = lane & 15, fq = lane >> 4;

  const u16* qkb = qkT + (long long)z*4096*128;
  const u16* vbb = vB  + (long long)z*512*4096;

  // staging geometry: one call = 512 thr x 16B = 8KB = 64 rows of 128B.
  const int srow  = lane >> 3;
  const int sslot = (lane & 7) ^ srow;       // pre-swizzled 16B source slot

  // Q fragments direct from global (loop-invariant, wave's 32 q-rows)
  bf16x8 qa[2][2];
  #pragma unroll
  for(int m=0;m<2;m++)
    #pragma unroll
    for(int kk=0;kk<2;kk++)
      qa[m][kk] = *reinterpret_cast<const bf16x8*>(
          &qkb[(long long)(q0 + wr*32 + m*16 + fr)*128 + kk*32 + fq*8]);

  // incrementing staging pointers (no per-iter 64-bit mul chains)
  const u16* kp  = qkb + (long long)(wid*8 + srow)*128 + 64 + sslot*8;
  const u16* vp0 = vbb + (long long)(c0 + wid*8 + srow)*4096 + sslot*8;

  // precomputed LDS fragment base offsets (swizzle mask = (fr&7)<<4 for all)
  const int xm   = (fr & 7) << 4;
  const int koff = (wc*16 + fr)*128 + ((fq*16) ^ xm);   // K frag (kk: ^64)
  const int pab  = (wr*32 + fr)*128 + ((fq*16) ^ xm);   // P frag (+m*2048, ^kk*64)
  const int vfb  = (wc*64 + fr)*128 + ((fq*16) ^ xm);   // V frag (+n*2048, ^kk*64)
  const int kdst = wid * 1024;                          // K staging LDS offset
  // P write offsets per r (row qr = fq*4+r; + wr*4096 + m*2048 at store)
  const int key2 = (wc*16 + fr)*2;
  int pwo[4];
  #pragma unroll
  for(int r=0;r<4;r++){
    int qr = fq*4 + r;
    pwo[r] = qr*128 + (key2 ^ ((qr & 7) << 4));
  }

  // prologue: K0 (1 call), V0 (4 calls)
  gload16(kp, (u16*)((char*)Ks + kdst));
  kp += 64*128;
  gload16(vp0,            &Vs[(  0 + wid*8)*64]);
  gload16(vp0 +  64*4096, &Vs[( 64 + wid*8)*64]);
  gload16(vp0 + 128*4096, &Vs[(128 + wid*8)*64]);
  gload16(vp0 + 192*4096, &Vs[(192 + wid*8)*64]);
  vp0 += 64;
  __syncthreads();

  f32x4 acc[2][4] = {};
  float rsacc[2][4] = {};

  for(int t=0;t<64;t++){
    const int kbase = (t & 1) ? 8192 : 0;
    // ---- S = Q . K^T: this wave's 32q x 16k tile ----
    bf16x8 kb0 = ldsrd(Ks, kbase + koff);
    bf16x8 kb1 = ldsrd(Ks, kbase + (koff ^ 64));
    f32x4 s[2] = {};
    #pragma unroll
    for(int m=0;m<2;m++){
      s[m] = __builtin_amdgcn_mfma_f32_16x16x32_bf16(qa[m][0], kb0, s[m], 0, 0, 0);
      s[m] = __builtin_amdgcn_mfma_f32_16x16x32_bf16(qa[m][1], kb1, s[m], 0, 0, 0);
    }

    // ---- P = exp(S) -> LDS (swizzled), accumulate row-sum partials ----
    #pragma unroll
    for(int m=0;m<2;m++){
      #pragma unroll
      for(int r=0;r<4;r++){
        float e = __expf(s[m][r]);
        rsacc[m][r] += e;
        *(u16*)((char*)Ps + (pwo[r] + wr*4096 + m*2048)) = f2bf(e);
      }
    }
    __syncthreads();   // B1: P visible; V(t) stage (issued end of t-1) drained

    // issue next K staging (drained at B2, hidden under PV)
    if(t+1 < 64){
      gload16(kp, (u16*)((char*)Ks + (kbase ^ 8192) + kdst));
      kp += 64*128;
    }

    // ---- PV: acc[32q x 64c] += P . V^T ----
    bf16x8 pa00 = ldsrd(Ps, pab);
    bf16x8 pa01 = ldsrd(Ps, pab ^ 64);
    bf16x8 pa10 = ldsrd(Ps, (pab + 2048));
    bf16x8 pa11 = ldsrd(Ps, (pab + 2048) ^ 64);
    __builtin_amdgcn_s_setprio(1);
    #pragma unroll
    for(int n=0;n<4;n++){
      bf16x8 v0 = ldsrd(Vs, vfb + n*2048);
      bf16x8 v1 = ldsrd(Vs, (vfb + n*2048) ^ 64);
      acc[0][n] = __builtin_amdgcn_mfma_f32_16x16x32_bf16(pa00, v0, acc[0][n], 0, 0, 0);
      acc[0][n] = __builtin_amdgcn_mfma_f32_16x16x32_bf16(pa01, v1, acc[0][n], 0, 0, 0);
      acc[1][n] = __builtin_amdgcn_mfma_f32_16x16x32_bf16(pa10, v0, acc[1][n], 0, 0, 0);
      acc[1][n] = __builtin_amdgcn_mfma_f32_16x16x32_bf16(pa11, v1, acc[1][n], 0, 0, 0);
    }
    __builtin_amdgcn_s_setprio(0);
    __syncthreads();   // B2: all Ps/Vs reads done; K(t+1) drained

    // issue next V staging (flies during QK/exp(t+1), drained at next B1)
    if(t+1 < 64){
      gload16(vp0,            &Vs[(  0 + wid*8)*64]);
      gload16(vp0 +  64*4096, &Vs[( 64 + wid*8)*64]);
      gload16(vp0 + 128*4096, &Vs[(128 + wid*8)*64]);
      gload16(vp0 + 192*4096, &Vs[(192 + wid*8)*64]);
      vp0 += 64;
    }
  }

  // ---- rowsum: reduce over the 16 key-lanes, then across wc quarters ----
  #pragma unroll
  for(int m=0;m<2;m++)
    #pragma unroll
    for(int r=0;r<4;r++){
      float v = rsacc[m][r];
      #pragma unroll
      for(int o=1;o<16;o<<=1) v += __shfl_xor(v, o);
      rsacc[m][r] = v;
    }
  if(fr == 0){
    #pragma unroll
    for(int m=0;m<2;m++)
      #pragma unroll
      for(int r=0;r<4;r++)
        RS[wr][wc][m*16 + fq*4 + r] = rsacc[m][r];
  }
  __syncthreads();

  const float g = gamma[0];
  #pragma unroll
  for(int m=0;m<2;m++){
    float inv[4];
    #pragma unroll
    for(int r=0;r<4;r++){
      int rloc = m*16 + fq*4 + r;
      inv[r] = g / (RS[wr][0][rloc] + RS[wr][1][rloc] +
                    RS[wr][2][rloc] + RS[wr][3][rloc]);
    }
    #pragma unroll
    for(int n=0;n<4;n++){
      #pragma unroll
      for(int r=0;r<4;r++){
        int qrow = q0 + wr*32 + m*16 + fq*4 + r;
        int c    = c0 + wc*64 + n*16 + fr;
        float xv = b2f(xfT[((long long)z*4096 + qrow)*512 + c]);
        pcT[((long long)z*4096 + qrow)*1024 + c] = f2bf(acc[m][n][r]*inv[r] + xv);
      }
    }
  }
}

// ---------------------------------------------------------------------------
// Channel softmax over 8 split-K bf16 partial slabs:
// catt[b][i][j] = softmax_j( sum_s part[b*8+s][i][j] )
// ---------------------------------------------------------------------------
__global__ __launch_bounds__(256) void softmax_sum8b(const u16* __restrict__ part,
                                                     u16* __restrict__ catt)
{
  const int row = blockIdx.x;            // b*512 + i
  const int b = row >> 9, i = row & 511;
  const int t = threadIdx.x;
  const int lane = t & 63, wid = t >> 6;
  float v0 = 0.f, v1 = 0.f;
  #pragma unroll
  for(int sl=0;sl<8;sl++){
    uint32_t pr = *reinterpret_cast<const uint32_t*>(
        &part[(((long long)(b*8 + sl)*512 + i)*512) + 2*t]);
    v0 += b2f((u16)pr);
    v1 += b2f((u16)(pr >> 16));
  }
  float m = fmaxf(v0, v1);
  #pragma unroll
  for(int o=32;o;o>>=1) m = fmaxf(m, __shfl_xor(m, o));
  __shared__ float sred[4];
  if(lane == 0) sred[wid] = m;
  __syncthreads();
  m = fmaxf(fmaxf(sred[0], sred[1]), fmaxf(sred[2], sred[3]));
  float e0 = __expf(v0 - m), e1 = __expf(v1 - m);
  float s = e0 + e1;
  #pragma unroll
  for(int o=32;o;o>>=1) s += __shfl_xor(s, o);
  __syncthreads();
  if(lane == 0) sred[wid] = s;
  __syncthreads();
  s = sred[0] + sred[1] + sred[2] + sred[3];
  float inv = 1.0f / s;
  uint32_t pk = (uint32_t)f2bf(e0 * inv) | ((uint32_t)f2bf(e1 * inv) << 16);
  *reinterpret_cast<uint32_t*>(&catt[(long long)row * 512 + 2*t]) = pk;
}

// ---------------------------------------------------------------------------
// One-shot weight prep: qw/kw/vw/fw f32 -> bf16 (float4 granularity) + bias cat
// ---------------------------------------------------------------------------
__global__ __launch_bounds__(256) void prep_weights(
    const float* __restrict__ qw, const float* __restrict__ kw,
    const float* __restrict__ vw, const float* __restrict__ fw,
    const float* __restrict__ qb, const float* __restrict__ kb,
    u16* __restrict__ qkwb, u16* __restrict__ vwb, u16* __restrict__ fwb,
    float* __restrict__ qkb)
{
  long long i = (long long)blockIdx.x*256 + threadIdx.x;
  const float* src; u16* dst; long long o;
  if(i < 8192){        src = qw; dst = qkwb;          o = i; }
  else if(i < 16384){  src = kw; dst = qkwb + 32768;  o = i - 8192; }
  else if(i < 81920){  src = vw; dst = vwb;           o = i - 16384; }
  else if(i < 212992){ src = fw; dst = fwb;           o = i - 81920; }
  else if(i < 213024){
    int t = (int)(i - 212992) * 4;
    #pragma unroll
    for(int j=0;j<4;j++) qkb[t+j] = (t+j < 64) ? qb[t+j] : kb[t+j-64];
    return;
  } else return;
  float4 v = reinterpret_cast<const float4*>(src)[o];
  ushort4 w;
  w.x = f2bf(v.x); w.y = f2bf(v.y); w.z = f2bf(v.z); w.w = f2bf(v.w);
  reinterpret_cast<ushort4*>(dst)[o] = w;
}

// x f32 [b][512][4096] -> xfb bf16 [b][512][4096] and xfT bf16 [b][4096][512]
__global__ __launch_bounds__(256) void transpose_cast(
    const float* __restrict__ x, u16* __restrict__ xfb, u16* __restrict__ xfT)
{
  __shared__ float tile[32][33];
  const int b  = blockIdx.z;
  const int n0 = blockIdx.x * 32, c0 = blockIdx.y * 32;
  const int tx = threadIdx.x, ty = threadIdx.y;  // 32 x 8
  const float* xp = x + (long long)b * 512 * 4096;
  #pragma unroll
  for(int i=0;i<4;i++){
    int c = c0 + ty + i*8;
    float v = xp[(long long)c*4096 + n0 + tx];
    tile[ty + i*8][tx] = v;
    xfb[((long long)b*512 + c)*4096 + n0 + tx] = f2bf(v);
  }
  __syncthreads();
  #pragma unroll
  for(int i=0;i<4;i++){
    int n = n0 + ty + i*8;
    xfT[((long long)b*4096 + n)*512 + c0 + tx] = f2bf(tile[tx][ty + i*8]);
  }
}

// reduce BN partials red[512][256][2] -> stat {mean, rstd}; 1 block/channel
__global__ __launch_bounds__(256) void bn_finalize(const float* __restrict__ red,
                                                   float* __restrict__ stat)
{
  const int ch = blockIdx.x;
  const int t = threadIdx.x, lane = t & 63, wid = t >> 6;
  float2 p = reinterpret_cast<const float2*>(red)[ch*256 + t];   // slot t
  float s = p.x, ss = p.y;
  #pragma unroll
  for(int o=32;o;o>>=1){ s += __shfl_xor(s,o); ss += __shfl_xor(ss,o); }
  __shared__ float sr[8];
  if(lane == 0){ sr[wid] = s; sr[wid+4] = ss; }
  __syncthreads();
  if(t == 0){
    float S  = sr[0]+sr[1]+sr[2]+sr[3];
    float SS = sr[4]+sr[5]+sr[6]+sr[7];
    float mean = S * (1.f/16384.f);
    float var  = SS * (1.f/16384.f) - mean*mean;
    stat[ch*2]   = mean;
    stat[ch*2+1] = rsqrtf(var + 1e-5f);
  }
}

// out[b][c][n] = relu((yT[b][n][c]-mean)*rstd*w + bb)  (transpose via LDS)
__global__ __launch_bounds__(256) void bn_apply_t(const u16* __restrict__ yT,
    const float* __restrict__ stat, const float* __restrict__ w,
    const float* __restrict__ bb, float* __restrict__ out)
{
  __shared__ float tile[32][33];
  const int b  = blockIdx.z;
  const int n0 = blockIdx.x * 32, c0 = blockIdx.y * 32;
  const int tx = threadIdx.x, ty = threadIdx.y;  // 32 x 8
  const int ch = c0 + tx;
  const float sc = w[ch] * stat[ch*2+1];
  const float sh = bb[ch] - stat[ch*2] * sc;
  #pragma unroll
  for(int i=0;i<4;i++){
    int n = n0 + ty + i*8;
    float v = b2f(yT[((long long)b*4096 + n)*512 + ch]);
    tile[ty + i*8][tx] = fmaxf(v*sc + sh, 0.f);
  }
  __syncthreads();
  #pragma unroll
  for(int i=0;i<4;i++){
    int c = c0 + ty + i*8;
    out[((long long)b*512 + c)*4096 + n0 + tx] = tile[tx][ty + i*8];
  }
}

extern "C" void kernel_launch(void* const* d_in, const int* in_sizes, int n_in,
                              void* d_out, int out_size, void* d_ws, size_t ws_size,
                              hipStream_t stream)
{
  const float* x     = (const float*)d_in[0];
  const float* qw    = (const float*)d_in[1];
  const float* qb    = (const float*)d_in[2];
  const float* kw    = (const float*)d_in[3];
  const float* kb    = (const float*)d_in[4];
  const float* vw    = (const float*)d_in[5];
  const float* vb    = (const float*)d_in[6];
  const float* gamma = (const float*)d_in[7];
  const float* beta  = (const float*)d_in[8];
  const float* fw    = (const float*)d_in[9];
  const float* fb    = (const float*)d_in[10];
  const float* bnw   = (const float*)d_in[11];
  const float* bnb   = (const float*)d_in[12];
  float* out = (float*)d_out;
  (void)in_sizes; (void)n_in; (void)out_size; (void)ws_size;

  char* base = (char*)d_ws;
  size_t off = 0;
  auto alloc = [&](size_t bytes)->char* {
    char* p = base + off;
    off += (bytes + 255) & ~(size_t)255;
    return p;
  };
  const long long NB = 4, Cc = 512, Nn = 4096;

  u16*   xfT  = (u16*)alloc((size_t)NB*Nn*Cc*2);     // [b][n][c]
  u16*   fwb  = (u16*)alloc((size_t)Cc*2*Cc*2);      // [512][1024] (alive thru fusion)
  // --- region dead by fusion time: yT aliases it (needs 16.8MB; has ~38.5) ---
  char*  region = (char*)(base + off);
  u16*   xfb  = (u16*)alloc((size_t)NB*Cc*Nn*2);     // [b][c][n]
  u16*   qkwb = (u16*)alloc((size_t)128*Cc*2);       // [128][512]
  float* qkb  = (float*)alloc(128*4);
  u16*   vwb  = (u16*)alloc((size_t)Cc*Cc*2);
  u16*   qkT  = (u16*)alloc((size_t)NB*Nn*128*2);    // [b][n][128]
  u16*   vB   = (u16*)alloc((size_t)NB*Cc*Nn*2);     // [b][c][n]
  // --- end region ---
  u16*   pcT  = (u16*)alloc((size_t)NB*Nn*1024*2);   // [b][n][pos|chan]
  u16*   epart= (u16*)alloc((size_t)32*Cc*Cc*2);     // energy partials bf16 [b*8+s]
  u16*   catt = (u16*)alloc((size_t)NB*Cc*Cc*2);
  float* stat = (float*)alloc((size_t)Cc*2*4);
  float* red  = (float*)alloc((size_t)Cc*256*2*4);   // BN partials [512][256][2]
  u16*   yT   = (u16*)region;                        // [b][4096][512] bf16

  // --- weights to bf16 (+ q/k stacked, bias concat) — one launch ---
  prep_weights<<<dim3(833), dim3(256), 0, stream>>>(qw, kw, vw, fw, qb, kb,
                                                    qkwb, vwb, fwb, qkb);
  // --- x -> xfb, xfT ---
  transpose_cast<<<dim3(128,16,4), dim3(32,8), 0, stream>>>(x, xfb, xfT);

  // --- projections: qkT[n,0:64]=q, [64:128]=k ; vB[c,n] ---
  gemm_bt<64,128,2,4,2,2,1><<<dim3(1,64,4), dim3(256), 0, stream>>>(
      xfT, Nn*Cc, 512, qkwb, 0, 512, qkT, Nn*128, 128, qkb, 512,
      nullptr, nullptr, 0, 0, nullptr);
  gemm_bt<128,128,4,4,1,2,1><<<dim3(32,4,4), dim3(256), 0, stream>>>(
      vwb, 0, 512, xfT, Nn*Cc, 512, vB, Cc*Nn, 4096, vb, 512,
      nullptr, nullptr, 0, 0, nullptr);

  // --- channel attention: energy (128^2 tile, split-K 8, bf16 partials) ---
  gemm_bt<128,128,4,4,0,2,1,8><<<dim3(4,4,32), dim3(256), 0, stream>>>(
      xfb, Cc*Nn, 4096, xfb, Cc*Nn, 4096, epart, Cc*Cc, 512, nullptr, 512,
      nullptr, nullptr, 0, 0, nullptr);
  softmax_sum8b<<<dim3(2048), dim3(256), 0, stream>>>(epart, catt);
  gemm_bt<128,128,4,4,0,3,1><<<dim3(4,32,4), dim3(256), 0, stream>>>(
      xfT, Nn*Cc, 512, catt, Cc*Cc, 512, pcT + 512, Nn*1024, 1024, nullptr, 512,
      beta, xfT, Nn*Cc, 512, nullptr);

  // --- position attention: fused flash kernel (pcT cols 0-511) ---
  flash_pos<<<dim3(64,2,4), dim3(512), 0, stream>>>(qkT, vB, xfT, pcT, gamma);

  // --- fusion conv (operand-swapped): yT[token][chan] = pcT . fwb^T + fb,
  //     fused per-column BN partials (pcT streams once; fwb L2-resident) ---
  gemm_bt<128,128,4,4,2,9,1><<<dim3(4,32,4), dim3(256), 0, stream>>>(
      pcT, Nn*1024, 1024, fwb, 0, 1024, yT, Nn*Cc, 512, fb, 1024,
      nullptr, nullptr, 0, 0, red);

  // --- BN finalize + apply (+ReLU, transpose) into f32 out ---
  bn_finalize<<<dim3(512), dim3(256), 0, stream>>>(red, stat);
  bn_apply_t<<<dim3(128,16,4), dim3(32,8), 0, stream>>>(yT, stat, bnw, bnb, out);
}